// Round 6
// baseline (81.963 us; speedup 1.0000x reference)
//
#include <hip/hip_runtime.h>
#include <math.h>

constexpr int Bn = 2048;
constexpr int Nn = 4096;
constexpr int TPB = 256;   // 4 waves

struct G {
    float4 w4, k0, k1, k2, p0, p1, p2;
};

__device__ __forceinline__ G loadg(const float* __restrict__ wb,
                                   const float* __restrict__ kpb,
                                   const float* __restrict__ psb,
                                   int idx)
{
    G g;
    g.w4 = *reinterpret_cast<const float4*>(wb + idx);
    g.k0 = *reinterpret_cast<const float4*>(kpb + idx);
    g.k1 = *reinterpret_cast<const float4*>(kpb + Nn + idx);
    g.k2 = *reinterpret_cast<const float4*>(kpb + 2 * Nn + idx);
    g.p0 = *reinterpret_cast<const float4*>(psb + idx);
    g.p1 = *reinterpret_cast<const float4*>(psb + Nn + idx);
    g.p2 = *reinterpret_cast<const float4*>(psb + 2 * Nn + idx);
    return g;
}

// ---------------- Kernel A: streaming partial sums ----------------
// One block per batch (2048 blocks x 4 waves = 8192 waves = 100% device
// wave capacity at 8 waves/SIMD). Depth-2 software pipeline keeps ~2 KB
// per wave in flight; launch_bounds(256,8) makes all blocks co-resident.
__global__ __launch_bounds__(TPB, 8)
void kabsch_stream(const float* __restrict__ kp,
                   const float* __restrict__ ps,
                   const float* __restrict__ wt,
                   float* __restrict__ ws)
{
    const int b   = blockIdx.x;
    const int tid = threadIdx.x;
    const float* kpb = kp + (size_t)b * 3 * Nn;
    const float* psb = ps + (size_t)b * 3 * Nn;
    const float* wb  = wt + (size_t)b * Nn;

    const int i0 = tid * 4;          // 4 groups of 1024 floats

    float acc[16];
#pragma unroll
    for (int i = 0; i < 16; ++i) acc[i] = 0.f;

#define ACCUM(GG, C) do {                                               \
        const float wj = GG.w4.C;                                       \
        const float a0 = GG.k0.C, a1 = GG.k1.C, a2 = GG.k2.C;           \
        const float q0 = GG.p0.C, q1 = GG.p1.C, q2 = GG.p2.C;           \
        const float wa0 = wj * a0, wa1 = wj * a1, wa2 = wj * a2;        \
        acc[0]  += wj;                                                  \
        acc[1]  += wa0;      acc[2]  += wa1;      acc[3]  += wa2;       \
        acc[4]  += wj * q0;  acc[5]  += wj * q1;  acc[6]  += wj * q2;   \
        acc[7]  += wa0 * q0; acc[8]  += wa0 * q1; acc[9]  += wa0 * q2;  \
        acc[10] += wa1 * q0; acc[11] += wa1 * q1; acc[12] += wa1 * q2;  \
        acc[13] += wa2 * q0; acc[14] += wa2 * q1; acc[15] += wa2 * q2;  \
    } while (0)
#define CONSUME(GG) ACCUM(GG, x); ACCUM(GG, y); ACCUM(GG, z); ACCUM(GG, w)

    // software pipeline: always ~1-2 groups (1-2 KB/wave) in flight
    G g0 = loadg(wb, kpb, psb, i0);
    G g1 = loadg(wb, kpb, psb, i0 + 1024);
    CONSUME(g0);
    G g2 = loadg(wb, kpb, psb, i0 + 2048);
    CONSUME(g1);
    G g3 = loadg(wb, kpb, psb, i0 + 3072);
    CONSUME(g2);
    CONSUME(g3);
#undef CONSUME
#undef ACCUM

    // wave butterfly reduction of 16 accumulators
#pragma unroll
    for (int i = 0; i < 16; ++i) {
        float v = acc[i];
#pragma unroll
        for (int off = 32; off > 0; off >>= 1) v += __shfl_down(v, off);
        acc[i] = v;
    }

    __shared__ float red[4][16];
    const int lane = tid & 63;
    const int wid  = tid >> 6;
    if (lane == 0) {
#pragma unroll
        for (int i = 0; i < 16; ++i) red[wid][i] = acc[i];
    }
    __syncthreads();
    if (tid < 16) {
        const float v = red[0][tid] + red[1][tid] + red[2][tid] + red[3][tid];
        ws[(size_t)b * 16 + tid] = v;
    }
}

// ---------------- Kernel B: parallel 3x3 Kabsch epilogue ----------------
// one THREAD per batch; 2048 threads = 8 blocks x 256
__global__ void kabsch_epilogue(const float* __restrict__ ws,
                                float* __restrict__ out)
{
    const int b = blockIdx.x * blockDim.x + threadIdx.x;
    if (b >= Bn) return;

    const float* p = ws + (size_t)b * 16;
    double s[16];
#pragma unroll
    for (int i = 0; i < 16; ++i) s[i] = (double)p[i];

    const double W    = s[0];
    const double invW = 1.0 / W;
    double kc[3] = { s[1] * invW, s[2] * invW, s[3] * invW };
    double pc[3] = { s[4] * invW, s[5] * invW, s[6] * invW };
    double H[3][3];
#pragma unroll
    for (int i = 0; i < 3; ++i)
#pragma unroll
        for (int j = 0; j < 3; ++j)
            H[i][j] = s[7 + i * 3 + j] * invW - kc[i] * pc[j];

    // A = H^T H (symmetric)
    double A[3][3];
#pragma unroll
    for (int i = 0; i < 3; ++i)
#pragma unroll
        for (int j = 0; j < 3; ++j)
            A[i][j] = H[0][i] * H[0][j] + H[1][i] * H[1][j] + H[2][i] * H[2][j];

    double V[3][3] = { {1,0,0}, {0,1,0}, {0,0,1} };

#define JROT(P,Q) do {                                                       \
        const double apq = A[P][Q];                                          \
        if (fabs(apq) > 1e-300) {                                            \
            const double th = (A[Q][Q] - A[P][P]) / (2.0 * apq);             \
            const double tt = copysign(1.0, th) / (fabs(th) + sqrt(1.0 + th * th)); \
            const double cc = 1.0 / sqrt(1.0 + tt * tt);                     \
            const double sn = tt * cc;                                       \
            _Pragma("unroll")                                                \
            for (int k = 0; k < 3; ++k) {                                    \
                const double akp = A[k][P], akq = A[k][Q];                   \
                A[k][P] = cc * akp - sn * akq;                               \
                A[k][Q] = sn * akp + cc * akq;                               \
            }                                                                \
            _Pragma("unroll")                                                \
            for (int k = 0; k < 3; ++k) {                                    \
                const double apk = A[P][k], aqk = A[Q][k];                   \
                A[P][k] = cc * apk - sn * aqk;                               \
                A[Q][k] = sn * apk + cc * aqk;                               \
            }                                                                \
            _Pragma("unroll")                                                \
            for (int k = 0; k < 3; ++k) {                                    \
                const double vkp = V[k][P], vkq = V[k][Q];                   \
                V[k][P] = cc * vkp - sn * vkq;                               \
                V[k][Q] = sn * vkp + cc * vkq;                               \
            }                                                                \
        }                                                                    \
    } while (0)

    for (int sweep = 0; sweep < 6; ++sweep) { JROT(0,1); JROT(0,2); JROT(1,2); }
#undef JROT

    double lam[3] = { A[0][0], A[1][1], A[2][2] };
#define CSWAP(I,J) if (lam[I] < lam[J]) {                                    \
        const double tl = lam[I]; lam[I] = lam[J]; lam[J] = tl;              \
        _Pragma("unroll")                                                    \
        for (int k = 0; k < 3; ++k) {                                        \
            const double tv = V[k][I]; V[k][I] = V[k][J]; V[k][J] = tv; }    \
    }
    CSWAP(0, 1); CSWAP(0, 2); CSWAP(1, 2);
#undef CSWAP

    double v0[3] = { V[0][0], V[1][0], V[2][0] };
    double v1[3] = { V[0][1], V[1][1], V[2][1] };
    double v2[3] = { v0[1] * v1[2] - v0[2] * v1[1],
                     v0[2] * v1[0] - v0[0] * v1[2],
                     v0[0] * v1[1] - v0[1] * v1[0] };

    double u0[3], u1[3];
#pragma unroll
    for (int i = 0; i < 3; ++i)
        u0[i] = H[i][0] * v0[0] + H[i][1] * v0[1] + H[i][2] * v0[2];
    {
        double n0 = sqrt(u0[0]*u0[0] + u0[1]*u0[1] + u0[2]*u0[2]);
        n0 = fmax(n0, 1e-300);
#pragma unroll
        for (int i = 0; i < 3; ++i) u0[i] /= n0;
    }
    {
        double b1[3];
#pragma unroll
        for (int i = 0; i < 3; ++i)
            b1[i] = H[i][0] * v1[0] + H[i][1] * v1[1] + H[i][2] * v1[2];
        const double dp = u0[0]*b1[0] + u0[1]*b1[1] + u0[2]*b1[2];
#pragma unroll
        for (int i = 0; i < 3; ++i) b1[i] -= dp * u0[i];
        double n1 = sqrt(b1[0]*b1[0] + b1[1]*b1[1] + b1[2]*b1[2]);
        if (n1 > 1e-150) {
#pragma unroll
            for (int i = 0; i < 3; ++i) u1[i] = b1[i] / n1;
        } else {
            double e[3] = { 0, 0, 0 };
            if (fabs(u0[0]) <= fabs(u0[1]) && fabs(u0[0]) <= fabs(u0[2])) e[0] = 1;
            else if (fabs(u0[1]) <= fabs(u0[2])) e[1] = 1;
            else e[2] = 1;
            double c1[3] = { u0[1]*e[2] - u0[2]*e[1],
                             u0[2]*e[0] - u0[0]*e[2],
                             u0[0]*e[1] - u0[1]*e[0] };
            double nc = sqrt(c1[0]*c1[0] + c1[1]*c1[1] + c1[2]*c1[2]);
            nc = fmax(nc, 1e-300);
#pragma unroll
            for (int i = 0; i < 3; ++i) u1[i] = c1[i] / nc;
        }
    }

    const double detH =
        H[0][0] * (H[1][1] * H[2][2] - H[1][2] * H[2][1]) -
        H[0][1] * (H[1][0] * H[2][2] - H[1][2] * H[2][0]) +
        H[0][2] * (H[1][0] * H[2][1] - H[1][1] * H[2][0]);
    const double d = (detH < 0.0) ? -1.0 : 1.0;

    double u2[3] = { d * (u0[1]*u1[2] - u0[2]*u1[1]),
                     d * (u0[2]*u1[0] - u0[0]*u1[2]),
                     d * (u0[0]*u1[1] - u0[1]*u1[0]) };

    double R[3][3];
#pragma unroll
    for (int i = 0; i < 3; ++i)
#pragma unroll
        for (int j = 0; j < 3; ++j)
            R[i][j] = v0[i] * u0[j] + v1[i] * u1[j] + d * v2[i] * u2[j];

    double t[3];
#pragma unroll
    for (int i = 0; i < 3; ++i)
        t[i] = pc[i] - (R[i][0] * kc[0] + R[i][1] * kc[1] + R[i][2] * kc[2]);

    float* outR = out + (size_t)b * 9;
    float* outT = out + (size_t)Bn * 9 + (size_t)b * 3;
#pragma unroll
    for (int i = 0; i < 3; ++i)
#pragma unroll
        for (int j = 0; j < 3; ++j)
            outR[i * 3 + j] = (float)R[i][j];
#pragma unroll
    for (int i = 0; i < 3; ++i) outT[i] = (float)t[i];
}

extern "C" void kernel_launch(void* const* d_in, const int* in_sizes, int n_in,
                              void* d_out, int out_size, void* d_ws, size_t ws_size,
                              hipStream_t stream) {
    const float* kp = (const float*)d_in[0];
    const float* ps = (const float*)d_in[1];
    const float* wt = (const float*)d_in[2];
    float* out = (float*)d_out;
    float* ws  = (float*)d_ws;
    kabsch_stream<<<Bn, TPB, 0, stream>>>(kp, ps, wt, ws);
    kabsch_epilogue<<<(Bn + 255) / 256, 256, 0, stream>>>(ws, out);
}

// Round 7
// 50.271 us; speedup vs baseline: 1.6304x; 1.6304x over previous
//
#include <hip/hip_runtime.h>
#include <math.h>

constexpr int Bn = 2048;
constexpr int Nn = 4096;
constexpr int TPB = 256;   // 4 waves

// async global->LDS, width 16B/lane; LDS dest is wave-uniform base + lane*16
#define GLL(SRC, FOFF)                                                        \
    __builtin_amdgcn_global_load_lds(                                         \
        (const __attribute__((address_space(1))) float*)(SRC),                \
        (__attribute__((address_space(3))) float*)(&lds[(FOFF)]), 16, 0, 0)

#define WAITV(N) do {                                                         \
        asm volatile("s_waitcnt vmcnt(" #N ")" ::: "memory");                 \
        __builtin_amdgcn_sched_barrier(0);                                    \
    } while (0)
#define WAITL() do {                                                          \
        asm volatile("s_waitcnt lgkmcnt(0)" ::: "memory");                    \
        __builtin_amdgcn_sched_barrier(0);                                    \
    } while (0)

// ---------------- Kernel A: streaming partial sums ----------------
// One block per batch. Per-wave ping-pong LDS staging via global_load_lds
// with counted vmcnt waits (never 0 mid-pipeline): 7 KB always in flight
// per wave, no barriers (each wave consumes exactly what it staged).
// Each wave writes its own 16 partial sums to ws[b*64 + wid*16 + i].
__global__ __launch_bounds__(TPB, 4)
void kabsch_stream(const float* __restrict__ kp,
                   const float* __restrict__ ps,
                   const float* __restrict__ wt,
                   float* __restrict__ ws)
{
    // 2 bufs x 7 rows x 4 waves x 256 floats = 57,344 B -> 2 blocks/CU
    __shared__ float lds[2 * 7 * 4 * 256];

    const int b    = blockIdx.x;
    const int tid  = threadIdx.x;
    const int lane = tid & 63;
    const int wid  = tid >> 6;

    const float* kpb = kp + (size_t)b * 3 * Nn;
    const float* psb = ps + (size_t)b * 3 * Nn;
    const float* wb  = wt + (size_t)b * Nn;

    const int ldsw = wid * 256;   // wave-uniform float offset inside a row slot

#define ISSUE(P, IT) do {                                                     \
        const int gi = (IT) * 1024 + tid * 4;                                 \
        GLL(kpb + gi,          (P) * 7168 + 0 * 1024 + ldsw);                 \
        GLL(kpb + Nn + gi,     (P) * 7168 + 1 * 1024 + ldsw);                 \
        GLL(kpb + 2 * Nn + gi, (P) * 7168 + 2 * 1024 + ldsw);                 \
        GLL(psb + gi,          (P) * 7168 + 3 * 1024 + ldsw);                 \
        GLL(psb + Nn + gi,     (P) * 7168 + 4 * 1024 + ldsw);                 \
        GLL(psb + 2 * Nn + gi, (P) * 7168 + 5 * 1024 + ldsw);                 \
        GLL(wb + gi,           (P) * 7168 + 6 * 1024 + ldsw);                 \
    } while (0)

    float acc[16];
#pragma unroll
    for (int i = 0; i < 16; ++i) acc[i] = 0.f;

#define ACCUM(W4, K0, K1, K2, P0, P1, P2, C) do {                       \
        const float wj = W4.C;                                          \
        const float a0 = K0.C, a1 = K1.C, a2 = K2.C;                    \
        const float q0 = P0.C, q1 = P1.C, q2 = P2.C;                    \
        const float wa0 = wj * a0, wa1 = wj * a1, wa2 = wj * a2;        \
        acc[0]  += wj;                                                  \
        acc[1]  += wa0;      acc[2]  += wa1;      acc[3]  += wa2;       \
        acc[4]  += wj * q0;  acc[5]  += wj * q1;  acc[6]  += wj * q2;   \
        acc[7]  += wa0 * q0; acc[8]  += wa0 * q1; acc[9]  += wa0 * q2;  \
        acc[10] += wa1 * q0; acc[11] += wa1 * q1; acc[12] += wa1 * q2;  \
        acc[13] += wa2 * q0; acc[14] += wa2 * q1; acc[15] += wa2 * q2;  \
    } while (0)

#define CONSUME(P) do {                                                       \
        const int fo = (P) * 7168 + ldsw + lane * 4;                          \
        const float4 k0 = *reinterpret_cast<const float4*>(&lds[fo + 0*1024]);\
        const float4 k1 = *reinterpret_cast<const float4*>(&lds[fo + 1*1024]);\
        const float4 k2 = *reinterpret_cast<const float4*>(&lds[fo + 2*1024]);\
        const float4 p0 = *reinterpret_cast<const float4*>(&lds[fo + 3*1024]);\
        const float4 p1 = *reinterpret_cast<const float4*>(&lds[fo + 4*1024]);\
        const float4 p2 = *reinterpret_cast<const float4*>(&lds[fo + 5*1024]);\
        const float4 w4 = *reinterpret_cast<const float4*>(&lds[fo + 6*1024]);\
        ACCUM(w4, k0, k1, k2, p0, p1, p2, x);                                 \
        ACCUM(w4, k0, k1, k2, p0, p1, p2, y);                                 \
        ACCUM(w4, k0, k1, k2, p0, p1, p2, z);                                 \
        ACCUM(w4, k0, k1, k2, p0, p1, p2, w);                                 \
    } while (0)

    // ---- pipeline: 4 iterations, 2 buffers, counted vmcnt ----
    ISSUE(0, 0);          // 7 outstanding
    ISSUE(1, 1);          // 14 outstanding
    WAITV(7);             // iter0 landed (7 newest may be in flight)
    CONSUME(0);
    WAITL();              // buf0 ds_reads drained before DMA overwrite
    ISSUE(0, 2);
    WAITV(7);             // iter1 landed
    CONSUME(1);
    WAITL();
    ISSUE(1, 3);
    WAITV(7);             // iter2 landed
    CONSUME(0);
    WAITV(0);             // iter3 landed (pipeline drain)
    CONSUME(1);

#undef CONSUME
#undef ACCUM
#undef ISSUE

    // per-wave butterfly reduction; lane 0 writes this wave's 16 partials
#pragma unroll
    for (int i = 0; i < 16; ++i) {
        float v = acc[i];
#pragma unroll
        for (int off = 32; off > 0; off >>= 1) v += __shfl_down(v, off);
        acc[i] = v;
    }
    if (lane == 0) {
        float* o = ws + (size_t)b * 64 + wid * 16;
        *reinterpret_cast<float4*>(o + 0)  = make_float4(acc[0],  acc[1],  acc[2],  acc[3]);
        *reinterpret_cast<float4*>(o + 4)  = make_float4(acc[4],  acc[5],  acc[6],  acc[7]);
        *reinterpret_cast<float4*>(o + 8)  = make_float4(acc[8],  acc[9],  acc[10], acc[11]);
        *reinterpret_cast<float4*>(o + 12) = make_float4(acc[12], acc[13], acc[14], acc[15]);
    }
}

// ---------------- Kernel B: parallel 3x3 Kabsch epilogue ----------------
// one THREAD per batch; sums the 4 wave partials in fp64, then solves.
__global__ void kabsch_epilogue(const float* __restrict__ ws,
                                float* __restrict__ out)
{
    const int b = blockIdx.x * blockDim.x + threadIdx.x;
    if (b >= Bn) return;

    const float* p = ws + (size_t)b * 64;
    double s[16];
#pragma unroll
    for (int i = 0; i < 16; ++i)
        s[i] = (double)p[i] + (double)p[16 + i] +
               (double)p[32 + i] + (double)p[48 + i];

    const double W    = s[0];
    const double invW = 1.0 / W;
    double kc[3] = { s[1] * invW, s[2] * invW, s[3] * invW };
    double pc[3] = { s[4] * invW, s[5] * invW, s[6] * invW };
    double H[3][3];
#pragma unroll
    for (int i = 0; i < 3; ++i)
#pragma unroll
        for (int j = 0; j < 3; ++j)
            H[i][j] = s[7 + i * 3 + j] * invW - kc[i] * pc[j];

    // A = H^T H (symmetric)
    double A[3][3];
#pragma unroll
    for (int i = 0; i < 3; ++i)
#pragma unroll
        for (int j = 0; j < 3; ++j)
            A[i][j] = H[0][i] * H[0][j] + H[1][i] * H[1][j] + H[2][i] * H[2][j];

    double V[3][3] = { {1,0,0}, {0,1,0}, {0,0,1} };

#define JROT(P,Q) do {                                                       \
        const double apq = A[P][Q];                                          \
        if (fabs(apq) > 1e-300) {                                            \
            const double th = (A[Q][Q] - A[P][P]) / (2.0 * apq);             \
            const double tt = copysign(1.0, th) / (fabs(th) + sqrt(1.0 + th * th)); \
            const double cc = 1.0 / sqrt(1.0 + tt * tt);                     \
            const double sn = tt * cc;                                       \
            _Pragma("unroll")                                                \
            for (int k = 0; k < 3; ++k) {                                    \
                const double akp = A[k][P], akq = A[k][Q];                   \
                A[k][P] = cc * akp - sn * akq;                               \
                A[k][Q] = sn * akp + cc * akq;                               \
            }                                                                \
            _Pragma("unroll")                                                \
            for (int k = 0; k < 3; ++k) {                                    \
                const double apk = A[P][k], aqk = A[Q][k];                   \
                A[P][k] = cc * apk - sn * aqk;                               \
                A[Q][k] = sn * apk + cc * aqk;                               \
            }                                                                \
            _Pragma("unroll")                                                \
            for (int k = 0; k < 3; ++k) {                                    \
                const double vkp = V[k][P], vkq = V[k][Q];                   \
                V[k][P] = cc * vkp - sn * vkq;                               \
                V[k][Q] = sn * vkp + cc * vkq;                               \
            }                                                                \
        }                                                                    \
    } while (0)

    for (int sweep = 0; sweep < 6; ++sweep) { JROT(0,1); JROT(0,2); JROT(1,2); }
#undef JROT

    double lam[3] = { A[0][0], A[1][1], A[2][2] };
#define CSWAP(I,J) if (lam[I] < lam[J]) {                                    \
        const double tl = lam[I]; lam[I] = lam[J]; lam[J] = tl;              \
        _Pragma("unroll")                                                    \
        for (int k = 0; k < 3; ++k) {                                        \
            const double tv = V[k][I]; V[k][I] = V[k][J]; V[k][J] = tv; }    \
    }
    CSWAP(0, 1); CSWAP(0, 2); CSWAP(1, 2);
#undef CSWAP

    double v0[3] = { V[0][0], V[1][0], V[2][0] };
    double v1[3] = { V[0][1], V[1][1], V[2][1] };
    double v2[3] = { v0[1] * v1[2] - v0[2] * v1[1],
                     v0[2] * v1[0] - v0[0] * v1[2],
                     v0[0] * v1[1] - v0[1] * v1[0] };

    double u0[3], u1[3];
#pragma unroll
    for (int i = 0; i < 3; ++i)
        u0[i] = H[i][0] * v0[0] + H[i][1] * v0[1] + H[i][2] * v0[2];
    {
        double n0 = sqrt(u0[0]*u0[0] + u0[1]*u0[1] + u0[2]*u0[2]);
        n0 = fmax(n0, 1e-300);
#pragma unroll
        for (int i = 0; i < 3; ++i) u0[i] /= n0;
    }
    {
        double b1[3];
#pragma unroll
        for (int i = 0; i < 3; ++i)
            b1[i] = H[i][0] * v1[0] + H[i][1] * v1[1] + H[i][2] * v1[2];
        const double dp = u0[0]*b1[0] + u0[1]*b1[1] + u0[2]*b1[2];
#pragma unroll
        for (int i = 0; i < 3; ++i) b1[i] -= dp * u0[i];
        double n1 = sqrt(b1[0]*b1[0] + b1[1]*b1[1] + b1[2]*b1[2]);
        if (n1 > 1e-150) {
#pragma unroll
            for (int i = 0; i < 3; ++i) u1[i] = b1[i] / n1;
        } else {
            double e[3] = { 0, 0, 0 };
            if (fabs(u0[0]) <= fabs(u0[1]) && fabs(u0[0]) <= fabs(u0[2])) e[0] = 1;
            else if (fabs(u0[1]) <= fabs(u0[2])) e[1] = 1;
            else e[2] = 1;
            double c1[3] = { u0[1]*e[2] - u0[2]*e[1],
                             u0[2]*e[0] - u0[0]*e[2],
                             u0[0]*e[1] - u0[1]*e[0] };
            double nc = sqrt(c1[0]*c1[0] + c1[1]*c1[1] + c1[2]*c1[2]);
            nc = fmax(nc, 1e-300);
#pragma unroll
            for (int i = 0; i < 3; ++i) u1[i] = c1[i] / nc;
        }
    }

    const double detH =
        H[0][0] * (H[1][1] * H[2][2] - H[1][2] * H[2][1]) -
        H[0][1] * (H[1][0] * H[2][2] - H[1][2] * H[2][0]) +
        H[0][2] * (H[1][0] * H[2][1] - H[1][1] * H[2][0]);
    const double d = (detH < 0.0) ? -1.0 : 1.0;

    double u2[3] = { d * (u0[1]*u1[2] - u0[2]*u1[1]),
                     d * (u0[2]*u1[0] - u0[0]*u1[2]),
                     d * (u0[0]*u1[1] - u0[1]*u1[0]) };

    double R[3][3];
#pragma unroll
    for (int i = 0; i < 3; ++i)
#pragma unroll
        for (int j = 0; j < 3; ++j)
            R[i][j] = v0[i] * u0[j] + v1[i] * u1[j] + d * v2[i] * u2[j];

    double t[3];
#pragma unroll
    for (int i = 0; i < 3; ++i)
        t[i] = pc[i] - (R[i][0] * kc[0] + R[i][1] * kc[1] + R[i][2] * kc[2]);

    float* outR = out + (size_t)b * 9;
    float* outT = out + (size_t)Bn * 9 + (size_t)b * 3;
#pragma unroll
    for (int i = 0; i < 3; ++i)
#pragma unroll
        for (int j = 0; j < 3; ++j)
            outR[i * 3 + j] = (float)R[i][j];
#pragma unroll
    for (int i = 0; i < 3; ++i) outT[i] = (float)t[i];
}

extern "C" void kernel_launch(void* const* d_in, const int* in_sizes, int n_in,
                              void* d_out, int out_size, void* d_ws, size_t ws_size,
                              hipStream_t stream) {
    const float* kp = (const float*)d_in[0];
    const float* ps = (const float*)d_in[1];
    const float* wt = (const float*)d_in[2];
    float* out = (float*)d_out;
    float* ws  = (float*)d_ws;
    kabsch_stream<<<Bn, TPB, 0, stream>>>(kp, ps, wt, ws);
    kabsch_epilogue<<<(Bn + 255) / 256, 256, 0, stream>>>(ws, out);
}

// Round 9
// 45.294 us; speedup vs baseline: 1.8096x; 1.1099x over previous
//
#include <hip/hip_runtime.h>
#include <math.h>

constexpr int Bn = 2048;
constexpr int Nn = 4096;
constexpr int TPB = 256;   // 4 waves

typedef float floatx4 __attribute__((ext_vector_type(4)));

struct G {
    floatx4 w4, k0, k1, k2, p0, p1, p2;
};

__device__ __forceinline__ floatx4 ntload(const float* p) {
    return __builtin_nontemporal_load(reinterpret_cast<const floatx4*>(p));
}

__device__ __forceinline__ G loadg(const float* __restrict__ wb,
                                   const float* __restrict__ kpb,
                                   const float* __restrict__ psb,
                                   int idx)
{
    G g;
    g.w4 = ntload(wb + idx);
    g.k0 = ntload(kpb + idx);
    g.k1 = ntload(kpb + Nn + idx);
    g.k2 = ntload(kpb + 2 * Nn + idx);
    g.p0 = ntload(psb + idx);
    g.p1 = ntload(psb + Nn + idx);
    g.p2 = ntload(psb + 2 * Nn + idx);
    return g;
}

// ---------------- Kernel A: streaming partial sums ----------------
// One block per batch; depth-2 software pipeline of 4 float4 groups.
// ALL input loads are non-temporal (nt): bypass L3 retention so the
// 229 MB input streams from HBM instead of thrashing the 256 MB L3.
__global__ __launch_bounds__(TPB, 4)
void kabsch_stream(const float* __restrict__ kp,
                   const float* __restrict__ ps,
                   const float* __restrict__ wt,
                   float* __restrict__ ws)
{
    const int b   = blockIdx.x;
    const int tid = threadIdx.x;
    const float* kpb = kp + (size_t)b * 3 * Nn;
    const float* psb = ps + (size_t)b * 3 * Nn;
    const float* wb  = wt + (size_t)b * Nn;

    const int i0 = tid * 4;

    float acc[16];
#pragma unroll
    for (int i = 0; i < 16; ++i) acc[i] = 0.f;

#define ACCUM(GG, C) do {                                               \
        const float wj = GG.w4.C;                                       \
        const float a0 = GG.k0.C, a1 = GG.k1.C, a2 = GG.k2.C;           \
        const float q0 = GG.p0.C, q1 = GG.p1.C, q2 = GG.p2.C;           \
        const float wa0 = wj * a0, wa1 = wj * a1, wa2 = wj * a2;        \
        acc[0]  += wj;                                                  \
        acc[1]  += wa0;      acc[2]  += wa1;      acc[3]  += wa2;       \
        acc[4]  += wj * q0;  acc[5]  += wj * q1;  acc[6]  += wj * q2;   \
        acc[7]  += wa0 * q0; acc[8]  += wa0 * q1; acc[9]  += wa0 * q2;  \
        acc[10] += wa1 * q0; acc[11] += wa1 * q1; acc[12] += wa1 * q2;  \
        acc[13] += wa2 * q0; acc[14] += wa2 * q1; acc[15] += wa2 * q2;  \
    } while (0)
#define CONSUME(GG) ACCUM(GG, x); ACCUM(GG, y); ACCUM(GG, z); ACCUM(GG, w)

    G g0 = loadg(wb, kpb, psb, i0);
    G g1 = loadg(wb, kpb, psb, i0 + 1024);
    CONSUME(g0);
    G g2 = loadg(wb, kpb, psb, i0 + 2048);
    CONSUME(g1);
    G g3 = loadg(wb, kpb, psb, i0 + 3072);
    CONSUME(g2);
    CONSUME(g3);
#undef CONSUME
#undef ACCUM

    // wave butterfly reduction of 16 accumulators
#pragma unroll
    for (int i = 0; i < 16; ++i) {
        float v = acc[i];
#pragma unroll
        for (int off = 32; off > 0; off >>= 1) v += __shfl_down(v, off);
        acc[i] = v;
    }

    __shared__ float red[4][16];
    const int lane = tid & 63;
    const int wid  = tid >> 6;
    if (lane == 0) {
#pragma unroll
        for (int i = 0; i < 16; ++i) red[wid][i] = acc[i];
    }
    __syncthreads();
    if (tid < 16) {
        const float v = red[0][tid] + red[1][tid] + red[2][tid] + red[3][tid];
        ws[(size_t)b * 16 + tid] = v;
    }
}

// ---------------- Kernel B: parallel 3x3 Kabsch epilogue (fp32) ----------------
// one THREAD per batch; fp32 Jacobi (5 sweeps) -- ~4x lower latency than fp64,
// accuracy floor is set by the fp32 streaming accumulation anyway.
__global__ void kabsch_epilogue(const float* __restrict__ ws,
                                float* __restrict__ out)
{
    const int b = blockIdx.x * blockDim.x + threadIdx.x;
    if (b >= Bn) return;

    const float* p = ws + (size_t)b * 16;
    float s[16];
#pragma unroll
    for (int i = 0; i < 16; ++i) s[i] = p[i];

    const float W    = s[0];
    const float invW = 1.0f / W;
    float kc[3] = { s[1] * invW, s[2] * invW, s[3] * invW };
    float pc[3] = { s[4] * invW, s[5] * invW, s[6] * invW };
    float H[3][3];
#pragma unroll
    for (int i = 0; i < 3; ++i)
#pragma unroll
        for (int j = 0; j < 3; ++j)
            H[i][j] = s[7 + i * 3 + j] * invW - kc[i] * pc[j];

    // A = H^T H (symmetric)
    float A[3][3];
#pragma unroll
    for (int i = 0; i < 3; ++i)
#pragma unroll
        for (int j = 0; j < 3; ++j)
            A[i][j] = H[0][i] * H[0][j] + H[1][i] * H[1][j] + H[2][i] * H[2][j];

    float V[3][3] = { {1,0,0}, {0,1,0}, {0,0,1} };

#define JROT(P,Q) do {                                                       \
        const float apq = A[P][Q];                                           \
        if (fabsf(apq) > 1e-30f) {                                           \
            const float th = (A[Q][Q] - A[P][P]) / (2.0f * apq);             \
            const float tt = copysignf(1.0f, th) / (fabsf(th) + sqrtf(1.0f + th * th)); \
            const float cc = rsqrtf(1.0f + tt * tt);                         \
            const float sn = tt * cc;                                        \
            _Pragma("unroll")                                                \
            for (int k = 0; k < 3; ++k) {                                    \
                const float akp = A[k][P], akq = A[k][Q];                    \
                A[k][P] = cc * akp - sn * akq;                               \
                A[k][Q] = sn * akp + cc * akq;                               \
            }                                                                \
            _Pragma("unroll")                                                \
            for (int k = 0; k < 3; ++k) {                                    \
                const float apk = A[P][k], aqk = A[Q][k];                    \
                A[P][k] = cc * apk - sn * aqk;                               \
                A[Q][k] = sn * apk + cc * aqk;                               \
            }                                                                \
            _Pragma("unroll")                                                \
            for (int k = 0; k < 3; ++k) {                                    \
                const float vkp = V[k][P], vkq = V[k][Q];                    \
                V[k][P] = cc * vkp - sn * vkq;                               \
                V[k][Q] = sn * vkp + cc * vkq;                               \
            }                                                                \
        }                                                                    \
    } while (0)

    for (int sweep = 0; sweep < 5; ++sweep) { JROT(0,1); JROT(0,2); JROT(1,2); }
#undef JROT

    float lam[3] = { A[0][0], A[1][1], A[2][2] };
#define CSWAP(I,J) if (lam[I] < lam[J]) {                                    \
        const float tl = lam[I]; lam[I] = lam[J]; lam[J] = tl;               \
        _Pragma("unroll")                                                    \
        for (int k = 0; k < 3; ++k) {                                        \
            const float tv = V[k][I]; V[k][I] = V[k][J]; V[k][J] = tv; }     \
    }
    CSWAP(0, 1); CSWAP(0, 2); CSWAP(1, 2);
#undef CSWAP

    float v0[3] = { V[0][0], V[1][0], V[2][0] };
    float v1[3] = { V[0][1], V[1][1], V[2][1] };
    float v2[3] = { v0[1] * v1[2] - v0[2] * v1[1],
                    v0[2] * v1[0] - v0[0] * v1[2],
                    v0[0] * v1[1] - v0[1] * v1[0] };

    float u0[3], u1[3];
#pragma unroll
    for (int i = 0; i < 3; ++i)
        u0[i] = H[i][0] * v0[0] + H[i][1] * v0[1] + H[i][2] * v0[2];
    {
        float n0 = sqrtf(u0[0]*u0[0] + u0[1]*u0[1] + u0[2]*u0[2]);
        n0 = fmaxf(n0, 1e-30f);
#pragma unroll
        for (int i = 0; i < 3; ++i) u0[i] /= n0;
    }
    {
        float b1[3];
#pragma unroll
        for (int i = 0; i < 3; ++i)
            b1[i] = H[i][0] * v1[0] + H[i][1] * v1[1] + H[i][2] * v1[2];
        const float dp = u0[0]*b1[0] + u0[1]*b1[1] + u0[2]*b1[2];
#pragma unroll
        for (int i = 0; i < 3; ++i) b1[i] -= dp * u0[i];
        float n1 = sqrtf(b1[0]*b1[0] + b1[1]*b1[1] + b1[2]*b1[2]);
        if (n1 > 1e-18f) {
#pragma unroll
            for (int i = 0; i < 3; ++i) u1[i] = b1[i] / n1;
        } else {
            float e[3] = { 0, 0, 0 };
            if (fabsf(u0[0]) <= fabsf(u0[1]) && fabsf(u0[0]) <= fabsf(u0[2])) e[0] = 1;
            else if (fabsf(u0[1]) <= fabsf(u0[2])) e[1] = 1;
            else e[2] = 1;
            float c1[3] = { u0[1]*e[2] - u0[2]*e[1],
                            u0[2]*e[0] - u0[0]*e[2],
                            u0[0]*e[1] - u0[1]*e[0] };
            float nc = sqrtf(c1[0]*c1[0] + c1[1]*c1[1] + c1[2]*c1[2]);
            nc = fmaxf(nc, 1e-30f);
#pragma unroll
            for (int i = 0; i < 3; ++i) u1[i] = c1[i] / nc;
        }
    }

    const float detH =
        H[0][0] * (H[1][1] * H[2][2] - H[1][2] * H[2][1]) -
        H[0][1] * (H[1][0] * H[2][2] - H[1][2] * H[2][0]) +
        H[0][2] * (H[1][0] * H[2][1] - H[1][1] * H[2][0]);
    const float d = (detH < 0.0f) ? -1.0f : 1.0f;

    float u2[3] = { d * (u0[1]*u1[2] - u0[2]*u1[1]),
                    d * (u0[2]*u1[0] - u0[0]*u1[2]),
                    d * (u0[0]*u1[1] - u0[1]*u1[0]) };

    float R[3][3];
#pragma unroll
    for (int i = 0; i < 3; ++i)
#pragma unroll
        for (int j = 0; j < 3; ++j)
            R[i][j] = v0[i] * u0[j] + v1[i] * u1[j] + d * v2[i] * u2[j];

    float t[3];
#pragma unroll
    for (int i = 0; i < 3; ++i)
        t[i] = pc[i] - (R[i][0] * kc[0] + R[i][1] * kc[1] + R[i][2] * kc[2]);

    float* outR = out + (size_t)b * 9;
    float* outT = out + (size_t)Bn * 9 + (size_t)b * 3;
#pragma unroll
    for (int i = 0; i < 3; ++i)
#pragma unroll
        for (int j = 0; j < 3; ++j)
            outR[i * 3 + j] = R[i][j];
#pragma unroll
    for (int i = 0; i < 3; ++i) outT[i] = t[i];
}

extern "C" void kernel_launch(void* const* d_in, const int* in_sizes, int n_in,
                              void* d_out, int out_size, void* d_ws, size_t ws_size,
                              hipStream_t stream) {
    const float* kp = (const float*)d_in[0];
    const float* ps = (const float*)d_in[1];
    const float* wt = (const float*)d_in[2];
    float* out = (float*)d_out;
    float* ws  = (float*)d_ws;
    kabsch_stream<<<Bn, TPB, 0, stream>>>(kp, ps, wt, ws);
    kabsch_epilogue<<<(Bn + 255) / 256, 256, 0, stream>>>(ws, out);
}